// Round 2
// baseline (2172.803 us; speedup 1.0000x reference)
//
#include <hip/hip_runtime.h>
#include <hip/hip_bf16.h>
#include <math.h>

#define DIM 896
#define NH 8
#define HD 112
#define BB 64
#define TT 8
#define KA 65
#define KT 512
#define NKEYS (TT + KA + KT)   // 585

// ------------------------------ GEMM ------------------------------
// C[rows x 896] = A[rows x 896] @ W[896 x 896] + bias, fused epilogue.
// rows always a multiple of 64; N = K = 896.
#define BM 64
#define BN 64
#define BK 16

#define EPI_NONE  0
#define EPI_ROPE  1
#define EPI_RESID 2
#define EPI_RELU  3

// -log2(10000)/56
#define NEG_L2_10K_OVER_56 (-0.2373327285062406f)

__global__ __launch_bounds__(256) void gemm_fused(
    const float* __restrict__ A, const float* __restrict__ W,
    const float* __restrict__ bias, float* __restrict__ Cf,
    __hip_bfloat16* __restrict__ Cb, int epi, int pos_mod,
    const float* __restrict__ resid)
{
  __shared__ float As[BK][BM + 4];   // [k][m], pad 4 -> stride 68 (16B-aligned rows)
  __shared__ float Bs[BK][BN + 4];   // [k][n]
  const int tid  = threadIdx.x;
  const int row0 = blockIdx.x * BM;
  const int col0 = blockIdx.y * BN;
  // A-tile load: 64 rows x 16 k = 1024 floats = 256 threads x float4 (along k)
  const int a_r = tid >> 2, a_k = (tid & 3) * 4;
  // B-tile load: 16 k x 64 n: thread -> (k = tid/16, n = (tid%16)*4)
  const int b_k = tid >> 4, b_c = (tid & 15) * 4;
  // micro-tile: 16x16 threads, each 4x4 outputs
  const int tm = tid >> 4, tn = tid & 15;

  float acc[4][4] = {};
  const float* Aptr = A + (size_t)(row0 + a_r) * DIM + a_k;
  const float* Wptr = W + (size_t)b_k * DIM + col0 + b_c;

  float4 av = *(const float4*)Aptr;
  float4 bv = *(const float4*)Wptr;

  for (int k0 = 0; k0 < DIM; k0 += BK) {
    __syncthreads();
    As[a_k + 0][a_r] = av.x;
    As[a_k + 1][a_r] = av.y;
    As[a_k + 2][a_r] = av.z;
    As[a_k + 3][a_r] = av.w;
    *(float4*)&Bs[b_k][b_c] = bv;
    __syncthreads();
    if (k0 + BK < DIM) {
      av = *(const float4*)(Aptr + (k0 + BK));
      bv = *(const float4*)(Wptr + (size_t)(k0 + BK) * DIM);
    }
#pragma unroll
    for (int kk = 0; kk < BK; ++kk) {
      float4 a4 = *(const float4*)&As[kk][tm * 4];
      float4 b4 = *(const float4*)&Bs[kk][tn * 4];
      float a[4] = {a4.x, a4.y, a4.z, a4.w};
      float b[4] = {b4.x, b4.y, b4.z, b4.w};
#pragma unroll
      for (int i = 0; i < 4; ++i)
#pragma unroll
        for (int j = 0; j < 4; ++j)
          acc[i][j] = fmaf(a[i], b[j], acc[i][j]);
    }
  }

  const int cbase = col0 + tn * 4;
  float bvals[4];
#pragma unroll
  for (int j = 0; j < 4; ++j) bvals[j] = bias[cbase + j];

#pragma unroll
  for (int i = 0; i < 4; ++i) {
    const int r = row0 + tm * 4 + i;
    float vals[4];
#pragma unroll
    for (int j = 0; j < 4; ++j) vals[j] = acc[i][j] + bvals[j];

    if (epi == EPI_ROPE) {
      const int pos = r % pos_mod;
      const float posf = (float)pos;
#pragma unroll
      for (int pp = 0; pp < 4; pp += 2) {
        // cbase is even and 112 is even, so d0 is even and d0+1 stays in-head.
        const int d0 = (cbase + pp) % HD;
        // inv[j] = 10000^(-j/56), emb[d] = pos * inv[d % 56]
        const float f0 = exp2f((float)(d0 % 56) * NEG_L2_10K_OVER_56);
        const float f1 = exp2f((float)((d0 + 1) % 56) * NEG_L2_10K_OVER_56);
        float c0, s0, c1, s1;
        __sincosf(posf * f0, &s0, &c0);
        __sincosf(posf * f1, &s1, &c1);
        const float x0 = vals[pp], x1 = vals[pp + 1];
        vals[pp]     = x0 * c0 - x1 * s0;
        vals[pp + 1] = x1 * c1 + x0 * s1;
      }
    } else if (epi == EPI_RESID) {
#pragma unroll
      for (int j = 0; j < 4; ++j) vals[j] += resid[(size_t)r * DIM + cbase + j];
    } else if (epi == EPI_RELU) {
#pragma unroll
      for (int j = 0; j < 4; ++j) vals[j] = fmaxf(vals[j], 0.f);
    }

    if (Cb) {
      __hip_bfloat16* o = Cb + (size_t)r * DIM + cbase;
#pragma unroll
      for (int j = 0; j < 4; ++j) o[j] = __float2bfloat16(vals[j]);
    } else {
      *(float4*)(Cf + (size_t)r * DIM + cbase) =
          make_float4(vals[0], vals[1], vals[2], vals[3]);
    }
  }
}

// ------------------------------ h_ad = concat(h_a, p) ------------------------------
__global__ __launch_bounds__(256) void build_had(
    const float* __restrict__ h_a, const float* __restrict__ p,
    float* __restrict__ had)
{
  const int idx = blockIdx.x * 256 + threadIdx.x;
  const int total = BB * KA * DIM;
  if (idx >= total) return;
  const int c = idx % DIM;
  const int row = idx / DIM;
  const int b = row / KA, j = row % KA;
  had[idx] = (j < KA - 1) ? h_a[((size_t)b * (KA - 1) + j) * DIM + c]
                          : p[(size_t)b * DIM + c];
}

// ------------------------------ attention ------------------------------
// one block per (b,h); 585 keys (8 self + 65 ad + 512 task)
__global__ __launch_bounds__(256) void attn_kernel(
    const float* __restrict__ q, const float* __restrict__ k_s,
    const float* __restrict__ k_a, const __hip_bfloat16* __restrict__ k_t,
    const float* __restrict__ v_s, const float* __restrict__ v_a,
    const __hip_bfloat16* __restrict__ v_t, const float* __restrict__ gate,
    float* __restrict__ out)
{
  __shared__ float qs[HD][TT];     // [d][t] so qs[d][0..7] is contiguous
  __shared__ float sc[TT][NKEYS];  // scores -> exp weights
  __shared__ float isum[TT];
  const int tid = threadIdx.x;
  const int b = blockIdx.x >> 3, h = blockIdx.x & 7;
  const float scale = 0.09449111825230681f;  // 1/sqrt(112)
  const float rg = tanhf(gate[0]);

  for (int idx = tid; idx < TT * HD; idx += 256) {
    const int t = idx / HD, d = idx % HD;
    qs[d][t] = q[(size_t)(b * TT + t) * DIM + h * HD + d];
  }
  __syncthreads();

  // phase 1: scores. thread-per-key.
  for (int k = tid; k < NKEYS; k += 256) {
    float dot[TT] = {};
    float s = scale;
    if (k < TT + KA) {
      const float* kp = (k < TT)
          ? (k_s + (size_t)(b * TT + k) * DIM + h * HD)
          : (k_a + (size_t)(b * KA + (k - TT)) * DIM + h * HD);
      for (int d = 0; d < HD; ++d) {
        const float kv = kp[d];
#pragma unroll
        for (int t = 0; t < TT; ++t) dot[t] = fmaf(qs[d][t], kv, dot[t]);
      }
    } else {
      const __hip_bfloat16* kp =
          k_t + (size_t)(b * KT + (k - TT - KA)) * DIM + h * HD;
      for (int d = 0; d < HD; ++d) {
        const float kv = __bfloat162float(kp[d]);
#pragma unroll
        for (int t = 0; t < TT; ++t) dot[t] = fmaf(qs[d][t], kv, dot[t]);
      }
      s = scale * rg;
    }
#pragma unroll
    for (int t = 0; t < TT; ++t) sc[t][k] = dot[t] * s;
  }
  __syncthreads();

  // phase 2: softmax per t; wave w handles t = w, w+4
  const int wave = tid >> 6, lane = tid & 63;
  for (int t = wave; t < TT; t += 4) {
    float m = -1e30f;
    for (int k = lane; k < NKEYS; k += 64) m = fmaxf(m, sc[t][k]);
#pragma unroll
    for (int o = 32; o >= 1; o >>= 1) m = fmaxf(m, __shfl_xor(m, o));
    float sum = 0.f;
    for (int k = lane; k < NKEYS; k += 64) {
      const float e = expf(sc[t][k] - m);
      sc[t][k] = e;
      sum += e;
    }
#pragma unroll
    for (int o = 32; o >= 1; o >>= 1) sum += __shfl_xor(sum, o);
    if (lane == 0) isum[t] = 1.f / sum;
  }
  __syncthreads();

  // phase 3: out[t][d] = sum_k w[t][k] * v[k][d]
  for (int idx = tid; idx < TT * HD; idx += 256) {
    const int t = idx / HD, d = idx % HD;
    float acc = 0.f;
    const float* vs = v_s + (size_t)(b * TT) * DIM + h * HD + d;
#pragma unroll
    for (int k = 0; k < TT; ++k) acc = fmaf(sc[t][k], vs[(size_t)k * DIM], acc);
    const float* va = v_a + (size_t)(b * KA) * DIM + h * HD + d;
    for (int k = 0; k < KA; ++k) acc = fmaf(sc[t][TT + k], va[(size_t)k * DIM], acc);
    const __hip_bfloat16* vt = v_t + (size_t)(b * KT) * DIM + h * HD + d;
    for (int k = 0; k < KT; ++k)
      acc = fmaf(sc[t][TT + KA + k], __bfloat162float(vt[(size_t)k * DIM]), acc);
    out[(size_t)(b * TT + t) * DIM + h * HD + d] = acc * isum[t];
  }
}

// ------------------------------ layernorm ------------------------------
__global__ __launch_bounds__(256) void ln_kernel(
    const float* __restrict__ y, const float* __restrict__ g,
    const float* __restrict__ beta, float* __restrict__ yn)
{
  __shared__ float s1[4], s2[4];
  const int r = blockIdx.x, tid = threadIdx.x;
  const float* row = y + (size_t)r * DIM;
  float sum = 0.f, sq = 0.f;
  for (int c = tid; c < DIM; c += 256) {
    const float v = row[c];
    sum += v;
    sq = fmaf(v, v, sq);
  }
#pragma unroll
  for (int o = 32; o >= 1; o >>= 1) {
    sum += __shfl_xor(sum, o);
    sq  += __shfl_xor(sq, o);
  }
  const int wave = tid >> 6, lane = tid & 63;
  if (lane == 0) { s1[wave] = sum; s2[wave] = sq; }
  __syncthreads();
  sum = s1[0] + s1[1] + s1[2] + s1[3];
  sq  = s2[0] + s2[1] + s2[2] + s2[3];
  const float mu = sum / DIM;
  const float var = sq / DIM - mu * mu;
  const float rstd = 1.f / sqrtf(var + 1e-5f);
  for (int c = tid; c < DIM; c += 256)
    yn[(size_t)r * DIM + c] = (row[c] - mu) * rstd * g[c] + beta[c];
}

// ------------------------------ launch ------------------------------
extern "C" void kernel_launch(void* const* d_in, const int* in_sizes, int n_in,
                              void* d_out, int out_size, void* d_ws, size_t ws_size,
                              hipStream_t stream)
{
  const float* x   = (const float*)d_in[0];
  const float* h_a = (const float*)d_in[1];
  const float* h_t = (const float*)d_in[2];
  const float* p   = (const float*)d_in[3];
  const float* Wq  = (const float*)d_in[4];  const float* bq  = (const float*)d_in[5];
  const float* Wks = (const float*)d_in[6];  const float* bks = (const float*)d_in[7];
  const float* Wvs = (const float*)d_in[8];  const float* bvs = (const float*)d_in[9];
  const float* Wka = (const float*)d_in[10]; const float* bka = (const float*)d_in[11];
  const float* Wva = (const float*)d_in[12]; const float* bva = (const float*)d_in[13];
  const float* Wkt = (const float*)d_in[14]; const float* bkt = (const float*)d_in[15];
  const float* Wvt = (const float*)d_in[16]; const float* bvt = (const float*)d_in[17];
  const float* Wo  = (const float*)d_in[18]; const float* bo  = (const float*)d_in[19];
  const float* Wf  = (const float*)d_in[20]; const float* bf_ = (const float*)d_in[21];
  const float* gate = (const float*)d_in[22];
  const float* ln_g = (const float*)d_in[23];
  const float* ln_b = (const float*)d_in[24];

  // workspace layout (floats). k_t/v_t stored bf16 (half a float each).
  const size_t N_HAD = (size_t)BB * KA * DIM;   // 3,727,360
  const size_t N_SM  = (size_t)BB * TT * DIM;   //   458,752
  const size_t N_T2  = (size_t)BB * KT * DIM / 2; // 14,680,064 (bf16 pairs)
  const size_t needed_floats = N_HAD * 3 + N_SM * 3 + N_T2 * 2; // 41,918,464
  // Guard: if ws is too small, do nothing (harness reports incorrect output,
  // NOT a container crash) — diagnostic for the infra-vs-ws question.
  if (ws_size < needed_floats * sizeof(float)) return;

  float* wsf = (float*)d_ws;
  size_t off = 0;
  float* had = wsf + off; off += N_HAD;
  float* qb  = wsf + off; off += N_SM;
  float* ksb = wsf + off; off += N_SM;
  float* vsb = wsf + off; off += N_SM;
  float* kab = wsf + off; off += N_HAD;
  float* vab = wsf + off; off += N_HAD;
  __hip_bfloat16* ktb = (__hip_bfloat16*)(wsf + off); off += N_T2;
  __hip_bfloat16* vtb = (__hip_bfloat16*)(wsf + off); off += N_T2;
  // had is dead after the k_a/v_a GEMMs -> reuse its space for the tail buffers
  float* attn_out = had;
  float* yb  = had + N_SM;
  float* ynb = had + 2 * N_SM;

  const int totalHad = (int)N_HAD;
  build_had<<<(totalHad + 255) / 256, 256, 0, stream>>>(h_a, p, had);

  dim3 blk(256);
  dim3 gS(BB * TT / BM, DIM / BN);   // (8, 14)
  dim3 gA(BB * KA / BM, DIM / BN);   // (65, 14)
  dim3 gT(BB * KT / BM, DIM / BN);   // (512, 14)

  gemm_fused<<<gS, blk, 0, stream>>>(x,   Wq,  bq,  qb,  nullptr, EPI_ROPE, TT, nullptr);
  gemm_fused<<<gS, blk, 0, stream>>>(x,   Wks, bks, ksb, nullptr, EPI_ROPE, TT, nullptr);
  gemm_fused<<<gS, blk, 0, stream>>>(x,   Wvs, bvs, vsb, nullptr, EPI_NONE, 1, nullptr);
  gemm_fused<<<gA, blk, 0, stream>>>(had, Wka, bka, kab, nullptr, EPI_ROPE, KA, nullptr);
  gemm_fused<<<gA, blk, 0, stream>>>(had, Wva, bva, vab, nullptr, EPI_NONE, 1, nullptr);
  gemm_fused<<<gT, blk, 0, stream>>>(h_t, Wkt, bkt, nullptr, ktb,  EPI_ROPE, KT, nullptr);
  gemm_fused<<<gT, blk, 0, stream>>>(h_t, Wvt, bvt, nullptr, vtb,  EPI_NONE, 1, nullptr);

  attn_kernel<<<BB * NH, blk, 0, stream>>>(qb, ksb, kab, ktb, vsb, vab, vtb, gate, attn_out);

  gemm_fused<<<gS, blk, 0, stream>>>(attn_out, Wo, bo, yb, nullptr, EPI_RESID, 1, x);
  ln_kernel<<<BB * TT, blk, 0, stream>>>(yb, ln_g, ln_b, ynb);
  gemm_fused<<<gS, blk, 0, stream>>>(ynb, Wf, bf_, (float*)d_out, nullptr, EPI_RELU, 1, nullptr);
}

// Round 3
// 1106.611 us; speedup vs baseline: 1.9635x; 1.9635x over previous
//
#include <hip/hip_runtime.h>
#include <hip/hip_bf16.h>
#include <math.h>

#define DIM 896
#define NH 8
#define HD 112
#define BB 64
#define TT 8
#define KA 65
#define KAPAD 4224   // 64*65 = 4160 padded to 33*128
#define KT 512
#define NKEYS (TT + KA + KT)   // 585

#define EPI_NONE  0
#define EPI_ROPE  1
#define EPI_RESID 2
#define EPI_RELU  3

// -log2(10000)/56
#define NEG_L2_10K_OVER_56 (-0.2373327285062406f)

#ifndef __has_builtin
#define __has_builtin(x) 0
#endif
#if __has_builtin(__builtin_amdgcn_global_load_lds)
#define HAS_GLL 1
#else
#define HAS_GLL 0
#endif

typedef __attribute__((ext_vector_type(8))) short bf16x8_t;   // 8 bf16 (4 VGPRs)
typedef __attribute__((ext_vector_type(4))) float f32x4_t;    // MFMA accumulator

__device__ __forceinline__ short f2bf(float f) {
  // RNE f32 -> bf16 (inputs finite)
  unsigned u = __float_as_uint(f);
  u += 0x7fffu + ((u >> 16) & 1u);
  return (short)(u >> 16);
}
__device__ __forceinline__ float bf2f(short s) {
  return __uint_as_float(((unsigned)(unsigned short)s) << 16);
}

// ---------------- weight transpose: W[k][n] f32 -> Wt[n][k] bf16 ----------------
__global__ __launch_bounds__(256) void wtrans(const float* __restrict__ W,
                                              short* __restrict__ Wt)
{
  __shared__ float t[32][33];
  const int bx = blockIdx.x;  // n tile
  const int by = blockIdx.y;  // k tile
  const int tx = threadIdx.x & 31, ty = threadIdx.x >> 5;  // 32 x 8
#pragma unroll
  for (int i = 0; i < 4; ++i)
    t[ty + i * 8][tx] = W[(size_t)(by * 32 + ty + i * 8) * DIM + bx * 32 + tx];
  __syncthreads();
#pragma unroll
  for (int i = 0; i < 4; ++i)
    Wt[(size_t)(bx * 32 + ty + i * 8) * DIM + by * 32 + tx] = f2bf(t[tx][ty + i * 8]);
}

// ---------------- MFMA GEMM ----------------
// C[M x 896] = A[M x 896](f32) @ W[896 x 896] + bias, W given transposed bf16 Wt[n][k].
// 128x128 tile, 4 waves, each wave 4x4 grid of 16x16x32 bf16 MFMA tiles.
// grid = (7, M/128): N-tile fastest so the 7 sharers of an A-stripe run together (L2/LLC reuse).
__global__ __launch_bounds__(256) void gemm_mfma(
    const float* __restrict__ A, const short* __restrict__ Wt,
    const float* __restrict__ bias, float* __restrict__ Cf,
    short* __restrict__ Cb, int epi, int pos_mod,
    const float* __restrict__ resid)
{
  __shared__ __align__(16) short As[128 * 32];  // [m][k] k-contig
  __shared__ __align__(16) short Bs[128 * 32];  // [n][k] k-contig
  const int tid = threadIdx.x;
  const int wave = tid >> 6, lane = tid & 63;
  const int col0 = blockIdx.x * 128;
  const int row0 = blockIdx.y * 128;
  const int wm = wave >> 1, wn = wave & 1;     // 2x2 wave quadrants of 64x64
  const int lm = lane & 15, lq = lane >> 4;

  // A staging: thread -> row am = tid>>1, k-half akh = (tid&1)*16
  const int am = tid >> 1, akh = (tid & 1) * 16;
  const float* Ap = A + (size_t)(row0 + am) * DIM + akh;
  // B staging: lane -> n = wave*16 + (lane>>2) (+64 for round 1), k-quarter (lane&3)*8
  const short* Wp = Wt + (size_t)(col0 + wave * 16 + (lane >> 2)) * DIM + (lane & 3) * 8;

  f32x4_t acc[4][4];
#pragma unroll
  for (int i = 0; i < 4; ++i)
#pragma unroll
    for (int j = 0; j < 4; ++j) acc[i][j] = (f32x4_t){0.f, 0.f, 0.f, 0.f};

  // prefetch A k-slab 0
  float4 a0 = *(const float4*)(Ap);
  float4 a1 = *(const float4*)(Ap + 4);
  float4 a2 = *(const float4*)(Ap + 8);
  float4 a3 = *(const float4*)(Ap + 12);

  for (int k0 = 0; k0 < DIM; k0 += 32) {
    __syncthreads();  // previous compute done before overwriting LDS
    bf16x8_t w0, w1;
    w0[0] = f2bf(a0.x); w0[1] = f2bf(a0.y); w0[2] = f2bf(a0.z); w0[3] = f2bf(a0.w);
    w0[4] = f2bf(a1.x); w0[5] = f2bf(a1.y); w0[6] = f2bf(a1.z); w0[7] = f2bf(a1.w);
    w1[0] = f2bf(a2.x); w1[1] = f2bf(a2.y); w1[2] = f2bf(a2.z); w1[3] = f2bf(a2.w);
    w1[4] = f2bf(a3.x); w1[5] = f2bf(a3.y); w1[6] = f2bf(a3.z); w1[7] = f2bf(a3.w);
    *(bf16x8_t*)&As[am * 32 + akh] = w0;
    *(bf16x8_t*)&As[am * 32 + akh + 8] = w1;

    const short* gB = Wp + k0;
#if HAS_GLL
    __builtin_amdgcn_global_load_lds(
        (const __attribute__((address_space(1))) unsigned*)gB,
        (__attribute__((address_space(3))) unsigned*)&Bs[wave * 16 * 32], 16, 0, 0);
    __builtin_amdgcn_global_load_lds(
        (const __attribute__((address_space(1))) unsigned*)(gB + (size_t)64 * DIM),
        (__attribute__((address_space(3))) unsigned*)&Bs[(64 + wave * 16) * 32], 16, 0, 0);
#else
    *(bf16x8_t*)&Bs[wave * 16 * 32 + lane * 8] = *(const bf16x8_t*)gB;
    *(bf16x8_t*)&Bs[(64 + wave * 16) * 32 + lane * 8] =
        *(const bf16x8_t*)(gB + (size_t)64 * DIM);
#endif
    if (k0 + 32 < DIM) {  // prefetch next A slab while B is in flight
      a0 = *(const float4*)(Ap + k0 + 32);
      a1 = *(const float4*)(Ap + k0 + 36);
      a2 = *(const float4*)(Ap + k0 + 40);
      a3 = *(const float4*)(Ap + k0 + 44);
    }
    __syncthreads();  // staging visible (vmcnt/lgkm drained)

    bf16x8_t af[4], bfm[4];
#pragma unroll
    for (int t = 0; t < 4; ++t)
      af[t] = *(const bf16x8_t*)&As[(wm * 64 + t * 16 + lm) * 32 + lq * 8];
#pragma unroll
    for (int t = 0; t < 4; ++t)
      bfm[t] = *(const bf16x8_t*)&Bs[(wn * 64 + t * 16 + lm) * 32 + lq * 8];
#pragma unroll
    for (int tm = 0; tm < 4; ++tm)
#pragma unroll
      for (int tn = 0; tn < 4; ++tn)
        acc[tm][tn] = __builtin_amdgcn_mfma_f32_16x16x32_bf16(
            af[tm], bfm[tn], acc[tm][tn], 0, 0, 0);
  }

  // ---------------- epilogue ----------------
  // C/D frag: row m = quad*4 + reg, col n = lane&15  (per tile)
#pragma unroll
  for (int tn = 0; tn < 4; ++tn) {
    const int col = col0 + wn * 64 + tn * 16 + lm;
    const float bv = bias[col];
    float fr = 0.f, sgn = 0.f;
    if (epi == EPI_ROPE) {
      const int d0 = col % HD;
      fr = exp2f((float)(d0 % 56) * NEG_L2_10K_OVER_56);
      sgn = (d0 & 1) ? 1.f : -1.f;
    }
#pragma unroll
    for (int tm = 0; tm < 4; ++tm) {
#pragma unroll
      for (int r = 0; r < 4; ++r) {
        const int row = row0 + wm * 64 + tm * 16 + lq * 4 + r;
        float v = acc[tm][tn][r] + bv;
        if (epi == EPI_ROPE) {
          const float prt = __shfl_xor(v, 1);  // partner col = lane^1, pre-rope
          float s, c;
          __sincosf((float)(row % pos_mod) * fr, &s, &c);
          v = v * c + sgn * prt * s;
        } else if (epi == EPI_RESID) {
          v += resid[(size_t)row * DIM + col];
        } else if (epi == EPI_RELU) {
          v = fmaxf(v, 0.f);
        }
        if (Cb) Cb[(size_t)row * DIM + col] = f2bf(v);
        else    Cf[(size_t)row * DIM + col] = v;
      }
    }
  }
}

// ---------------- h_ad = concat(h_a, p), fp32, zero-padded to 4224 rows ----------------
__global__ __launch_bounds__(256) void build_had(
    const float* __restrict__ h_a, const float* __restrict__ p,
    float* __restrict__ had)
{
  const int idx = blockIdx.x * 256 + threadIdx.x;
  const int total = KAPAD * DIM;
  if (idx >= total) return;
  const int c = idx % DIM;
  const int row = idx / DIM;
  if (row >= BB * KA) { had[idx] = 0.f; return; }
  const int b = row / KA, j = row % KA;
  had[idx] = (j < KA - 1) ? h_a[((size_t)b * (KA - 1) + j) * DIM + c]
                          : p[(size_t)b * DIM + c];
}

// ---------------- attention: one block per (b,h); 585 keys ----------------
__global__ __launch_bounds__(256) void attn_kernel(
    const float* __restrict__ q, const float* __restrict__ k_s,
    const short* __restrict__ k_a, const short* __restrict__ k_t,
    const float* __restrict__ v_s, const short* __restrict__ v_a,
    const short* __restrict__ v_t, const float* __restrict__ gate,
    float* __restrict__ out)
{
  __shared__ float qs[HD][TT];
  __shared__ float sc[TT][NKEYS];
  __shared__ float isum[TT];
  const int tid = threadIdx.x;
  const int b = blockIdx.x >> 3, h = blockIdx.x & 7;
  const float scale = 0.09449111825230681f;  // 1/sqrt(112)
  const float rg = tanhf(gate[0]);

  for (int idx = tid; idx < TT * HD; idx += 256) {
    const int t = idx / HD, d = idx % HD;
    qs[d][t] = q[(size_t)(b * TT + t) * DIM + h * HD + d];
  }
  __syncthreads();

  for (int k = tid; k < NKEYS; k += 256) {
    float dot[TT] = {};
    float s = scale;
    if (k < TT) {
      const float* kp = k_s + (size_t)(b * TT + k) * DIM + h * HD;
      for (int d = 0; d < HD; ++d) {
        const float kv = kp[d];
#pragma unroll
        for (int t = 0; t < TT; ++t) dot[t] = fmaf(qs[d][t], kv, dot[t]);
      }
    } else if (k < TT + KA) {
      const short* kp = k_a + (size_t)(b * KA + (k - TT)) * DIM + h * HD;
      for (int d = 0; d < HD; ++d) {
        const float kv = bf2f(kp[d]);
#pragma unroll
        for (int t = 0; t < TT; ++t) dot[t] = fmaf(qs[d][t], kv, dot[t]);
      }
    } else {
      const short* kp = k_t + (size_t)(b * KT + (k - TT - KA)) * DIM + h * HD;
      for (int d = 0; d < HD; ++d) {
        const float kv = bf2f(kp[d]);
#pragma unroll
        for (int t = 0; t < TT; ++t) dot[t] = fmaf(qs[d][t], kv, dot[t]);
      }
      s = scale * rg;
    }
#pragma unroll
    for (int t = 0; t < TT; ++t) sc[t][k] = dot[t] * s;
  }
  __syncthreads();

  const int wave = tid >> 6, lane = tid & 63;
  for (int t = wave; t < TT; t += 4) {
    float m = -1e30f;
    for (int k = lane; k < NKEYS; k += 64) m = fmaxf(m, sc[t][k]);
#pragma unroll
    for (int o = 32; o >= 1; o >>= 1) m = fmaxf(m, __shfl_xor(m, o));
    float sum = 0.f;
    for (int k = lane; k < NKEYS; k += 64) {
      const float e = expf(sc[t][k] - m);
      sc[t][k] = e;
      sum += e;
    }
#pragma unroll
    for (int o = 32; o >= 1; o >>= 1) sum += __shfl_xor(sum, o);
    if (lane == 0) isum[t] = 1.f / sum;
  }
  __syncthreads();

  for (int idx = tid; idx < TT * HD; idx += 256) {
    const int t = idx / HD, d = idx % HD;
    float acc = 0.f;
    const float* vs = v_s + (size_t)(b * TT) * DIM + h * HD + d;
#pragma unroll
    for (int k = 0; k < TT; ++k) acc = fmaf(sc[t][k], vs[(size_t)k * DIM], acc);
    const short* va = v_a + (size_t)(b * KA) * DIM + h * HD + d;
    for (int k = 0; k < KA; ++k)
      acc = fmaf(sc[t][TT + k], bf2f(va[(size_t)k * DIM]), acc);
    const short* vt = v_t + (size_t)(b * KT) * DIM + h * HD + d;
    for (int k = 0; k < KT; ++k)
      acc = fmaf(sc[t][TT + KA + k], bf2f(vt[(size_t)k * DIM]), acc);
    out[(size_t)(b * TT + t) * DIM + h * HD + d] = acc * isum[t];
  }
}

// ---------------- layernorm ----------------
__global__ __launch_bounds__(256) void ln_kernel(
    const float* __restrict__ y, const float* __restrict__ g,
    const float* __restrict__ beta, float* __restrict__ yn)
{
  __shared__ float s1[4], s2[4];
  const int r = blockIdx.x, tid = threadIdx.x;
  const float* row = y + (size_t)r * DIM;
  float sum = 0.f, sq = 0.f;
  for (int c = tid; c < DIM; c += 256) {
    const float v = row[c];
    sum += v;
    sq = fmaf(v, v, sq);
  }
#pragma unroll
  for (int o = 32; o >= 1; o >>= 1) {
    sum += __shfl_xor(sum, o);
    sq  += __shfl_xor(sq, o);
  }
  const int wave = tid >> 6, lane = tid & 63;
  if (lane == 0) { s1[wave] = sum; s2[wave] = sq; }
  __syncthreads();
  sum = s1[0] + s1[1] + s1[2] + s1[3];
  sq  = s2[0] + s2[1] + s2[2] + s2[3];
  const float mu = sum / DIM;
  const float var = sq / DIM - mu * mu;
  const float rstd = 1.f / sqrtf(var + 1e-5f);
  for (int c = tid; c < DIM; c += 256)
    yn[(size_t)r * DIM + c] = (row[c] - mu) * rstd * g[c] + beta[c];
}

// ---------------- launch ----------------
extern "C" void kernel_launch(void* const* d_in, const int* in_sizes, int n_in,
                              void* d_out, int out_size, void* d_ws, size_t ws_size,
                              hipStream_t stream)
{
  const float* x   = (const float*)d_in[0];
  const float* h_a = (const float*)d_in[1];
  const float* h_t = (const float*)d_in[2];
  const float* p   = (const float*)d_in[3];
  const float* Wq  = (const float*)d_in[4];  const float* bq  = (const float*)d_in[5];
  const float* Wks = (const float*)d_in[6];  const float* bks = (const float*)d_in[7];
  const float* Wvs = (const float*)d_in[8];  const float* bvs = (const float*)d_in[9];
  const float* Wka = (const float*)d_in[10]; const float* bka = (const float*)d_in[11];
  const float* Wva = (const float*)d_in[12]; const float* bva = (const float*)d_in[13];
  const float* Wkt = (const float*)d_in[14]; const float* bkt = (const float*)d_in[15];
  const float* Wvt = (const float*)d_in[16]; const float* bvt = (const float*)d_in[17];
  const float* Wo  = (const float*)d_in[18]; const float* bo  = (const float*)d_in[19];
  const float* Wf  = (const float*)d_in[20]; const float* bf_ = (const float*)d_in[21];
  const float* gate = (const float*)d_in[22];
  const float* ln_g = (const float*)d_in[23];
  const float* ln_b = (const float*)d_in[24];

  // workspace (float units). Total = 41,918,464 floats = round-2's proven-safe size.
  const size_t N_HAD = (size_t)KAPAD * DIM;          // 3,784,704 f32
  const size_t N_SM  = (size_t)BB * TT * DIM;        //   458,752 f32
  const size_t N_AD2 = (size_t)KAPAD * DIM / 2;      // 1,892,352 (bf16 as f32 units)
  const size_t N_T2  = (size_t)BB * KT * DIM / 2;    // 14,680,064
  const size_t N_WT  = (size_t)9 * DIM * DIM / 2;    // 3,612,672
  const size_t needed = N_HAD + 3 * N_SM + 2 * N_AD2 + 2 * N_T2 + N_WT;
  if (ws_size < needed * sizeof(float)) return;  // fail loud (wrong output), not UB

  float* wsf = (float*)d_ws;
  size_t off = 0;
  float* had = wsf + off; off += N_HAD;
  float* qb  = wsf + off; off += N_SM;
  float* ksb = wsf + off; off += N_SM;
  float* vsb = wsf + off; off += N_SM;
  short* kab = (short*)(wsf + off); off += N_AD2;
  short* vab = (short*)(wsf + off); off += N_AD2;
  short* ktb = (short*)(wsf + off); off += N_T2;
  short* vtb = (short*)(wsf + off); off += N_T2;
  short* WtA = (short*)(wsf + off); off += N_WT;
  // had region is dead after the k_a/v_a GEMMs -> reuse for tail buffers
  float* attn_out = had;
  float* yb  = had + N_SM;
  float* ynb = had + 2 * N_SM;

  // 0) transpose+convert the 9 weights to bf16 Wt[n][k]
  const float* Ws[9] = {Wq, Wks, Wvs, Wka, Wva, Wkt, Wvt, Wo, Wf};
  for (int i = 0; i < 9; ++i)
    wtrans<<<dim3(28, 28), 256, 0, stream>>>(Ws[i], WtA + (size_t)i * DIM * DIM);
  short* WtQ  = WtA + 0 * (size_t)DIM * DIM;
  short* WtKs = WtA + 1 * (size_t)DIM * DIM;
  short* WtVs = WtA + 2 * (size_t)DIM * DIM;
  short* WtKa = WtA + 3 * (size_t)DIM * DIM;
  short* WtVa = WtA + 4 * (size_t)DIM * DIM;
  short* WtKt = WtA + 5 * (size_t)DIM * DIM;
  short* WtVt = WtA + 6 * (size_t)DIM * DIM;
  short* WtO  = WtA + 7 * (size_t)DIM * DIM;
  short* WtF  = WtA + 8 * (size_t)DIM * DIM;

  build_had<<<((int)N_HAD + 255) / 256, 256, 0, stream>>>(h_a, p, had);

  dim3 blk(256);
  dim3 gS(7, BB * TT / 128);    // (7, 4)
  dim3 gA(7, KAPAD / 128);      // (7, 33)
  dim3 gT(7, BB * KT / 128);    // (7, 256)

  gemm_mfma<<<gS, blk, 0, stream>>>(x,   WtQ,  bq,  qb,  nullptr, EPI_ROPE, TT, nullptr);
  gemm_mfma<<<gS, blk, 0, stream>>>(x,   WtKs, bks, ksb, nullptr, EPI_ROPE, TT, nullptr);
  gemm_mfma<<<gS, blk, 0, stream>>>(x,   WtVs, bvs, vsb, nullptr, EPI_NONE, 1, nullptr);
  gemm_mfma<<<gA, blk, 0, stream>>>(had, WtKa, bka, nullptr, kab, EPI_ROPE, KA, nullptr);
  gemm_mfma<<<gA, blk, 0, stream>>>(had, WtVa, bva, nullptr, vab, EPI_NONE, 1, nullptr);
  gemm_mfma<<<gT, blk, 0, stream>>>(h_t, WtKt, bkt, nullptr, ktb, EPI_ROPE, KT, nullptr);
  gemm_mfma<<<gT, blk, 0, stream>>>(h_t, WtVt, bvt, nullptr, vtb, EPI_NONE, 1, nullptr);

  attn_kernel<<<BB * NH, blk, 0, stream>>>(qb, ksb, kab, ktb, vsb, vab, vtb, gate, attn_out);

  gemm_mfma<<<gS, blk, 0, stream>>>(attn_out, WtO, bo, yb, nullptr, EPI_RESID, 1, x);
  ln_kernel<<<BB * TT, blk, 0, stream>>>(yb, ln_g, ln_b, ynb);
  gemm_mfma<<<gS, blk, 0, stream>>>(ynb, WtF, bf_, (float*)d_out, nullptr, EPI_RELU, 1, nullptr);
}

// Round 4
// 829.854 us; speedup vs baseline: 2.6183x; 1.3335x over previous
//
#include <hip/hip_runtime.h>
#include <hip/hip_bf16.h>
#include <math.h>

#define DIM 896
#define DD  (DIM * DIM)
#define NH 8
#define HD 112
#define BB 64
#define TT 8
#define KA 65
#define KAPAD 4224   // 64*65 = 4160 padded to 33*128
#define KT 512
#define NKEYS (TT + KA + KT)   // 585
#define CH 4096                // h_t conversion chunk rows (8 chunks)

#define EPI_NONE  0
#define EPI_ROPE  1
#define EPI_RESID 2
#define EPI_RELU  3

// -log2(10000)/56
#define NEG_L2_10K_OVER_56 (-0.2373327285062406f)

#ifndef __has_builtin
#define __has_builtin(x) 0
#endif
#if __has_builtin(__builtin_amdgcn_global_load_lds)
#define HAS_GLL 1
#else
#define HAS_GLL 0
#endif

typedef __attribute__((ext_vector_type(8))) short bf16x8_t;   // 8 bf16 (4 VGPRs)
typedef __attribute__((ext_vector_type(4))) float f32x4_t;    // MFMA accumulator

__device__ __forceinline__ short f2bf(float f) {
  unsigned u = __float_as_uint(f);
  u += 0x7fffu + ((u >> 16) & 1u);
  return (short)(u >> 16);
}
__device__ __forceinline__ float bf2f(short s) {
  return __uint_as_float(((unsigned)(unsigned short)s) << 16);
}

// ---------------- 9-way weight transpose: W[k][n] f32 -> Wt[n][k] bf16 ----------------
struct W9 { const float* w[9]; };

__global__ __launch_bounds__(256) void wtrans(W9 ws, short* __restrict__ Wt)
{
  __shared__ float t[32][33];
  const float* W = ws.w[blockIdx.z];
  short* dst = Wt + (size_t)blockIdx.z * DD;
  const int bx = blockIdx.x, by = blockIdx.y;
  const int tx = threadIdx.x & 31, ty = threadIdx.x >> 5;
#pragma unroll
  for (int i = 0; i < 4; ++i)
    t[ty + i * 8][tx] = W[(size_t)(by * 32 + ty + i * 8) * DIM + bx * 32 + tx];
  __syncthreads();
#pragma unroll
  for (int i = 0; i < 4; ++i)
    dst[(size_t)(bx * 32 + ty + i * 8) * DIM + by * 32 + tx] = f2bf(t[tx][ty + i * 8]);
}

// ---------------- fp32 -> bf16 elementwise (n8 = n/8 vector groups) ----------------
__global__ __launch_bounds__(256) void convert_bf16(
    const float* __restrict__ src, short* __restrict__ dst, int n8)
{
  const int i = blockIdx.x * 256 + threadIdx.x;
  if (i >= n8) return;
  const float4 a = ((const float4*)src)[i * 2];
  const float4 b = ((const float4*)src)[i * 2 + 1];
  bf16x8_t o;
  o[0] = f2bf(a.x); o[1] = f2bf(a.y); o[2] = f2bf(a.z); o[3] = f2bf(a.w);
  o[4] = f2bf(b.x); o[5] = f2bf(b.y); o[6] = f2bf(b.z); o[7] = f2bf(b.w);
  ((bf16x8_t*)dst)[i] = o;
}

// ---------------- h_ad = concat(h_a, p) -> bf16, zero-padded to 4224 rows ----------------
__global__ __launch_bounds__(256) void build_had(
    const float* __restrict__ h_a, const float* __restrict__ p,
    short* __restrict__ had)
{
  const int i = blockIdx.x * 256 + threadIdx.x;  // one per 8 elements
  const int total = KAPAD * DIM / 8;
  if (i >= total) return;
  const int c = (i % 112) * 8;
  const int row = i / 112;
  bf16x8_t o;
  if (row >= BB * KA) {
#pragma unroll
    for (int j = 0; j < 8; ++j) o[j] = 0;
  } else {
    const int b = row / KA, j = row % KA;
    const float* src = (j < KA - 1) ? h_a + ((size_t)b * (KA - 1) + j) * DIM + c
                                    : p + (size_t)b * DIM + c;
    const float4 a = *(const float4*)src;
    const float4 d = *(const float4*)(src + 4);
    o[0] = f2bf(a.x); o[1] = f2bf(a.y); o[2] = f2bf(a.z); o[3] = f2bf(a.w);
    o[4] = f2bf(d.x); o[5] = f2bf(d.y); o[6] = f2bf(d.z); o[7] = f2bf(d.w);
  }
  ((bf16x8_t*)had)[i] = o;
}

// ---------------- MFMA GEMM (m97 structure: gll both operands) ----------------
// C[M x N] = A[M x 896](bf16) @ Wt[N x 896](bf16, n-major) + bias, N = nsubs*896.
// 128x128 tile, BK=32, 4 waves x (4x4 of 16x16x32). Each block's 128 cols lie in
// exactly one 896-col sub-matrix (sub = blockIdx.x / 7), each with its own epilogue.
struct EpiCfg {
  const float* bias[3];
  float* outF[3];
  short* outB[3];
  const float* resid;
  int epi[3];
  int pos_mod[3];
  int row_off;   // global row offset (h_t chunking)
};

__global__ __launch_bounds__(256) void gemm_bf16(
    const short* __restrict__ A, const short* __restrict__ Wt, EpiCfg cfg)
{
  __shared__ __align__(16) short As[128 * 32];  // [m][k] 64 B rows
  __shared__ __align__(16) short Bs[128 * 32];  // [n][k]
  const int tid = threadIdx.x;
  const int wave = tid >> 6, lane = tid & 63;
  const int sub = blockIdx.x / 7;
  const int col0 = (blockIdx.x % 7) * 128;      // within sub
  const int row0 = blockIdx.y * 128;
  const int wm = wave >> 1, wn = wave & 1;
  const int lm = lane & 15, lq = lane >> 4;

  // staging source: lane -> row-in-16 = lane>>2, k-octet = (lane&3)*8
  const int sm = lane >> 2, sk = (lane & 3) * 8;
  const short* Ag0 = A + (size_t)(row0 + wave * 32 + sm) * DIM + sk;
  const short* Ag1 = Ag0 + (size_t)16 * DIM;
  const short* Wg0 = Wt + (size_t)(sub * DIM + col0 + wave * 32 + sm) * DIM + sk;
  const short* Wg1 = Wg0 + (size_t)16 * DIM;

  f32x4_t acc[4][4];
#pragma unroll
  for (int i = 0; i < 4; ++i)
#pragma unroll
    for (int j = 0; j < 4; ++j) acc[i][j] = (f32x4_t){0.f, 0.f, 0.f, 0.f};

  for (int k0 = 0; k0 < DIM; k0 += 32) {
    __syncthreads();
#if HAS_GLL
    __builtin_amdgcn_global_load_lds(
        (const __attribute__((address_space(1))) unsigned*)(Ag0 + k0),
        (__attribute__((address_space(3))) unsigned*)&As[(wave * 32) * 32], 16, 0, 0);
    __builtin_amdgcn_global_load_lds(
        (const __attribute__((address_space(1))) unsigned*)(Ag1 + k0),
        (__attribute__((address_space(3))) unsigned*)&As[(wave * 32 + 16) * 32], 16, 0, 0);
    __builtin_amdgcn_global_load_lds(
        (const __attribute__((address_space(1))) unsigned*)(Wg0 + k0),
        (__attribute__((address_space(3))) unsigned*)&Bs[(wave * 32) * 32], 16, 0, 0);
    __builtin_amdgcn_global_load_lds(
        (const __attribute__((address_space(1))) unsigned*)(Wg1 + k0),
        (__attribute__((address_space(3))) unsigned*)&Bs[(wave * 32 + 16) * 32], 16, 0, 0);
#else
    {
      const int m = tid >> 1, kh = (tid & 1) * 16;
      *(bf16x8_t*)&As[m * 32 + kh] =
          *(const bf16x8_t*)(A + (size_t)(row0 + m) * DIM + k0 + kh);
      *(bf16x8_t*)&As[m * 32 + kh + 8] =
          *(const bf16x8_t*)(A + (size_t)(row0 + m) * DIM + k0 + kh + 8);
      *(bf16x8_t*)&Bs[m * 32 + kh] =
          *(const bf16x8_t*)(Wt + (size_t)(sub * DIM + col0 + m) * DIM + k0 + kh);
      *(bf16x8_t*)&Bs[m * 32 + kh + 8] =
          *(const bf16x8_t*)(Wt + (size_t)(sub * DIM + col0 + m) * DIM + k0 + kh + 8);
    }
#endif
    __syncthreads();

    bf16x8_t af[4], bfr[4];
#pragma unroll
    for (int t = 0; t < 4; ++t)
      af[t] = *(const bf16x8_t*)&As[(wm * 64 + t * 16 + lm) * 32 + lq * 8];
#pragma unroll
    for (int t = 0; t < 4; ++t)
      bfr[t] = *(const bf16x8_t*)&Bs[(wn * 64 + t * 16 + lm) * 32 + lq * 8];
#pragma unroll
    for (int tm = 0; tm < 4; ++tm)
#pragma unroll
      for (int tn = 0; tn < 4; ++tn)
        acc[tm][tn] = __builtin_amdgcn_mfma_f32_16x16x32_bf16(
            af[tm], bfr[tn], acc[tm][tn], 0, 0, 0);
  }

  // epilogue — C/D frag: row = lq*4 + reg, col = lm (per 16x16 tile)
  const float* bias = cfg.bias[sub];
  float* outF = cfg.outF[sub];
  short* outB = cfg.outB[sub];
  const int epi = cfg.epi[sub], pm = cfg.pos_mod[sub];
#pragma unroll
  for (int tn = 0; tn < 4; ++tn) {
    const int col = col0 + wn * 64 + tn * 16 + lm;
    const float bv = bias[col];
    float fr = 0.f, sgn = 0.f;
    if (epi == EPI_ROPE) {
      const int d0 = col % HD;
      fr = exp2f((float)(d0 % 56) * NEG_L2_10K_OVER_56);
      sgn = (d0 & 1) ? 1.f : -1.f;
    }
#pragma unroll
    for (int tm = 0; tm < 4; ++tm) {
#pragma unroll
      for (int r = 0; r < 4; ++r) {
        const int grow = cfg.row_off + row0 + wm * 64 + tm * 16 + lq * 4 + r;
        float v = acc[tm][tn][r] + bv;
        if (epi == EPI_ROPE) {
          const float prt = __shfl_xor(v, 1);  // partner col (lane^1), pre-rope
          float s, c;
          __sincosf((float)(grow % pm) * fr, &s, &c);
          v = v * c + sgn * prt * s;
        } else if (epi == EPI_RESID) {
          v += cfg.resid[(size_t)grow * DIM + col];
        } else if (epi == EPI_RELU) {
          v = fmaxf(v, 0.f);
        }
        if (outB) outB[(size_t)grow * DIM + col] = f2bf(v);
        else      outF[(size_t)grow * DIM + col] = v;
      }
    }
  }
}

// ---------------- attention: one block per (b,h); 585 keys, all bf16 ----------------
__global__ __launch_bounds__(256) void attn_kernel(
    const short* __restrict__ q, const short* __restrict__ k_s,
    const short* __restrict__ k_a, const short* __restrict__ k_t,
    const short* __restrict__ v_s, const short* __restrict__ v_a,
    const short* __restrict__ v_t, const float* __restrict__ gate,
    short* __restrict__ out)
{
  __shared__ float qs[HD][TT];
  __shared__ float sc[TT][NKEYS];
  __shared__ float isum[TT];
  const int tid = threadIdx.x;
  const int b = blockIdx.x >> 3, h = blockIdx.x & 7;
  const float scale = 0.09449111825230681f;  // 1/sqrt(112)
  const float rg = tanhf(gate[0]);

  for (int idx = tid; idx < TT * HD; idx += 256) {
    const int t = idx / HD, d = idx % HD;
    qs[d][t] = bf2f(q[(size_t)(b * TT + t) * DIM + h * HD + d]);
  }
  __syncthreads();

  for (int k = tid; k < NKEYS; k += 256) {
    float dot[TT] = {};
    float s = scale;
    const short* kp;
    if (k < TT) {
      kp = k_s + (size_t)(b * TT + k) * DIM + h * HD;
    } else if (k < TT + KA) {
      kp = k_a + (size_t)(b * KA + (k - TT)) * DIM + h * HD;
    } else {
      kp = k_t + (size_t)(b * KT + (k - TT - KA)) * DIM + h * HD;
      s = scale * rg;
    }
    for (int d8 = 0; d8 < HD; d8 += 8) {
      const bf16x8_t kv8 = *(const bf16x8_t*)(kp + d8);
#pragma unroll
      for (int j = 0; j < 8; ++j) {
        const float kv = bf2f(kv8[j]);
#pragma unroll
        for (int t = 0; t < TT; ++t) dot[t] = fmaf(qs[d8 + j][t], kv, dot[t]);
      }
    }
#pragma unroll
    for (int t = 0; t < TT; ++t) sc[t][k] = dot[t] * s;
  }
  __syncthreads();

  const int wave = tid >> 6, lane = tid & 63;
  for (int t = wave; t < TT; t += 4) {
    float m = -1e30f;
    for (int k = lane; k < NKEYS; k += 64) m = fmaxf(m, sc[t][k]);
#pragma unroll
    for (int o = 32; o >= 1; o >>= 1) m = fmaxf(m, __shfl_xor(m, o));
    float sum = 0.f;
    for (int k = lane; k < NKEYS; k += 64) {
      const float e = expf(sc[t][k] - m);
      sc[t][k] = e;
      sum += e;
    }
#pragma unroll
    for (int o = 32; o >= 1; o >>= 1) sum += __shfl_xor(sum, o);
    if (lane == 0) isum[t] = 1.f / sum;
  }
  __syncthreads();

  for (int idx = tid; idx < TT * HD; idx += 256) {
    const int t = idx / HD, d = idx % HD;
    float acc = 0.f;
    const short* vs = v_s + (size_t)(b * TT) * DIM + h * HD + d;
#pragma unroll
    for (int k = 0; k < TT; ++k)
      acc = fmaf(sc[t][k], bf2f(vs[(size_t)k * DIM]), acc);
    const short* va = v_a + (size_t)(b * KA) * DIM + h * HD + d;
    for (int k = 0; k < KA; ++k)
      acc = fmaf(sc[t][TT + k], bf2f(va[(size_t)k * DIM]), acc);
    const short* vt = v_t + (size_t)(b * KT) * DIM + h * HD + d;
    for (int k = 0; k < KT; ++k)
      acc = fmaf(sc[t][TT + KA + k], bf2f(vt[(size_t)k * DIM]), acc);
    out[(size_t)(b * TT + t) * DIM + h * HD + d] = f2bf(acc * isum[t]);
  }
}

// ---------------- layernorm: fp32 in -> bf16 out ----------------
__global__ __launch_bounds__(256) void ln_kernel(
    const float* __restrict__ y, const float* __restrict__ g,
    const float* __restrict__ beta, short* __restrict__ yn)
{
  __shared__ float s1[4], s2[4];
  const int r = blockIdx.x, tid = threadIdx.x;
  const float* row = y + (size_t)r * DIM;
  float sum = 0.f, sq = 0.f;
  for (int c = tid; c < DIM; c += 256) {
    const float v = row[c];
    sum += v;
    sq = fmaf(v, v, sq);
  }
#pragma unroll
  for (int o = 32; o >= 1; o >>= 1) {
    sum += __shfl_xor(sum, o);
    sq  += __shfl_xor(sq, o);
  }
  const int wave = tid >> 6, lane = tid & 63;
  if (lane == 0) { s1[wave] = sum; s2[wave] = sq; }
  __syncthreads();
  sum = s1[0] + s1[1] + s1[2] + s1[3];
  sq  = s2[0] + s2[1] + s2[2] + s2[3];
  const float mu = sum / DIM;
  const float var = sq / DIM - mu * mu;
  const float rstd = 1.f / sqrtf(var + 1e-5f);
  for (int c = tid; c < DIM; c += 256)
    yn[(size_t)r * DIM + c] = f2bf((row[c] - mu) * rstd * g[c] + beta[c]);
}

// ---------------- launch ----------------
extern "C" void kernel_launch(void* const* d_in, const int* in_sizes, int n_in,
                              void* d_out, int out_size, void* d_ws, size_t ws_size,
                              hipStream_t stream)
{
  const float* x   = (const float*)d_in[0];
  const float* h_a = (const float*)d_in[1];
  const float* h_t = (const float*)d_in[2];
  const float* p   = (const float*)d_in[3];
  const float* Wq  = (const float*)d_in[4];  const float* bq  = (const float*)d_in[5];
  const float* Wks = (const float*)d_in[6];  const float* bks = (const float*)d_in[7];
  const float* Wvs = (const float*)d_in[8];  const float* bvs = (const float*)d_in[9];
  const float* Wka = (const float*)d_in[10]; const float* bka = (const float*)d_in[11];
  const float* Wva = (const float*)d_in[12]; const float* bva = (const float*)d_in[13];
  const float* Wkt = (const float*)d_in[14]; const float* bkt = (const float*)d_in[15];
  const float* Wvt = (const float*)d_in[16]; const float* bvt = (const float*)d_in[17];
  const float* Wo  = (const float*)d_in[18]; const float* bo  = (const float*)d_in[19];
  const float* Wf  = (const float*)d_in[20]; const float* bf_ = (const float*)d_in[21];
  const float* gate = (const float*)d_in[22];
  const float* ln_g = (const float*)d_in[23];
  const float* ln_b = (const float*)d_in[24];

  // ---- workspace layout (bytes). Total = 161.94 MB < round-3-proven 167.67 MB ----
  const size_t SZ_HAD = (size_t)KAPAD * DIM * 2;        // bf16
  const size_t SZ_SM  = (size_t)BB * TT * DIM * 2;      // bf16 small [512 x 896]
  const size_t SZ_T   = (size_t)BB * KT * DIM * 2;      // bf16 [32768 x 896]
  const size_t SZ_WT  = (size_t)9 * DD * 2;             // 9 weights bf16
  const size_t needed = SZ_HAD * 3 + SZ_SM * 6 + SZ_T * 2 + SZ_WT
                        + (size_t)BB * TT * DIM * 4;    // + yb fp32
  if (ws_size < needed) return;  // fail loud, not UB

  char* wsp = (char*)d_ws;
  short* hadb = (short*)wsp; wsp += SZ_HAD;
  short* xb   = (short*)wsp; wsp += SZ_SM;
  short* qb   = (short*)wsp; wsp += SZ_SM;
  short* ksb  = (short*)wsp; wsp += SZ_SM;
  short* vsb  = (short*)wsp; wsp += SZ_SM;
  short* kab  = (short*)wsp; wsp += SZ_HAD;
  short* vab  = (short*)wsp; wsp += SZ_HAD;
  short* ktb  = (short*)wsp; wsp += SZ_T;
  short* vtb  = (short*)wsp; wsp += SZ_T;
  short* WtA  = (short*)wsp; wsp += SZ_WT;
  short* attn_outb = (short*)wsp; wsp += SZ_SM;
  float* yb   = (float*)wsp; wsp += (size_t)BB * TT * DIM * 4;
  short* ynb  = (short*)wsp; wsp += SZ_SM;
  // h_t conversion scratch aliases weights 0..4 (Wq..Wva), dead once GEMM-S/A ran.
  // CH*DIM*2 = 7,340,032 B < 5*DD*2 = 8,028,160 B; live WtKt starts at 5*DD. ✓
  short* scratch = WtA;

  dim3 blk(256);

  // 0) transpose all 9 weights -> bf16 [n][k], concatenated
  W9 w9; const float* Ws[9] = {Wq, Wks, Wvs, Wka, Wva, Wkt, Wvt, Wo, Wf};
  for (int i = 0; i < 9; ++i) w9.w[i] = Ws[i];
  wtrans<<<dim3(28, 28, 9), blk, 0, stream>>>(w9, WtA);

  // 1) activations -> bf16
  convert_bf16<<<(BB * TT * DIM / 8 + 255) / 256, blk, 0, stream>>>(x, xb, BB * TT * DIM / 8);
  build_had<<<(KAPAD * DIM / 8 + 255) / 256, blk, 0, stream>>>(h_a, p, hadb);

  // 2) fused S-group GEMM: [q | k_s | v_s] = xb @ [Wq|Wks|Wvs]
  {
    EpiCfg c = {};
    c.bias[0] = bq;  c.outB[0] = qb;  c.epi[0] = EPI_ROPE; c.pos_mod[0] = TT;
    c.bias[1] = bks; c.outB[1] = ksb; c.epi[1] = EPI_ROPE; c.pos_mod[1] = TT;
    c.bias[2] = bvs; c.outB[2] = vsb; c.epi[2] = EPI_NONE; c.pos_mod[2] = 1;
    gemm_bf16<<<dim3(21, BB * TT / 128), blk, 0, stream>>>(xb, WtA, c);
  }
  // 3) fused A-group GEMM: [k_a | v_a] = hadb @ [Wka|Wva]
  {
    EpiCfg c = {};
    c.bias[0] = bka; c.outB[0] = kab; c.epi[0] = EPI_ROPE; c.pos_mod[0] = KA;
    c.bias[1] = bva; c.outB[1] = vab; c.epi[1] = EPI_NONE; c.pos_mod[1] = 1;
    gemm_bf16<<<dim3(14, KAPAD / 128), blk, 0, stream>>>(hadb, WtA + (size_t)3 * DD, c);
  }
  // 4) chunked T-group GEMM: [k_t | v_t] = h_t @ [Wkt|Wvt], h_t converted per chunk
  for (int m0 = 0; m0 < BB * KT; m0 += CH) {
    convert_bf16<<<(CH * DIM / 8 + 255) / 256, blk, 0, stream>>>(
        h_t + (size_t)m0 * DIM, scratch, CH * DIM / 8);
    EpiCfg c = {};
    c.bias[0] = bkt; c.outB[0] = ktb; c.epi[0] = EPI_ROPE; c.pos_mod[0] = KT;
    c.bias[1] = bvt; c.outB[1] = vtb; c.epi[1] = EPI_NONE; c.pos_mod[1] = 1;
    c.row_off = m0;
    gemm_bf16<<<dim3(14, CH / 128), blk, 0, stream>>>(scratch, WtA + (size_t)5 * DD, c);
  }

  // 5) attention
  attn_kernel<<<BB * NH, blk, 0, stream>>>(qb, ksb, kab, ktb, vsb, vab, vtb, gate,
                                           attn_outb);

  // 6) out-proj + residual (fp32 out), LN (bf16 out), FFN + ReLU (fp32 d_out)
  {
    EpiCfg c = {};
    c.bias[0] = bo; c.outF[0] = yb; c.epi[0] = EPI_RESID; c.pos_mod[0] = 1;
    c.resid = x;
    gemm_bf16<<<dim3(7, BB * TT / 128), blk, 0, stream>>>(attn_outb, WtA + (size_t)7 * DD, c);
  }
  ln_kernel<<<BB * TT, blk, 0, stream>>>(yb, ln_g, ln_b, ynb);
  {
    EpiCfg c = {};
    c.bias[0] = bf_; c.outF[0] = (float*)d_out; c.epi[0] = EPI_RELU; c.pos_mod[0] = 1;
    gemm_bf16<<<dim3(7, BB * TT / 128), blk, 0, stream>>>(ynb, WtA + (size_t)8 * DD, c);
  }
}